// Round 5
// baseline (173.318 us; speedup 1.0000x reference)
//
#include <hip/hip_runtime.h>

#define VOCAB 10000
#define EMB   16
#define HID   32
#define BATCH 4096
#define TLEN  512

// ---------------------------------------------------------------------------
// Kernel 1: P[v][j] = b[j] + sum_e emb[v][e] * Wx[e][j]   (fp32 table in ws)
// ---------------------------------------------------------------------------
__global__ __launch_bounds__(256) void rnn_proj(
    const float* __restrict__ emb, const float* __restrict__ Wx,
    const float* __restrict__ bias, float* __restrict__ P)
{
    int tid = blockIdx.x * 256 + threadIdx.x;
    if (tid >= VOCAB * HID) return;
    int v = tid >> 5;
    int j = tid & 31;
    float acc = bias[j];
    const float* ev = emb + v * EMB;
#pragma unroll
    for (int e = 0; e < EMB; ++e) {
        acc = fmaf(ev[e], Wx[e * HID + j], acc);
    }
    P[tid] = acc;
}

// ---------------------------------------------------------------------------
// Kernel 2: DPP scan. Wave = 2 batches x 32 j-lanes. Lane g holds h_g in a
// REGISTER (no LDS h storage, no ds_read gather). The dot product
// z_j = sum_i h_i * Wh[i][j] runs as 32 v_fmac_f32_dpp row_ror:s (16 on h,
// 16 on hswz = ds_swizzle(h, lane^16)). Weight tables are built with lane
// indices transported through the SAME DPP op, so the rotation direction is
// correct by construction. Tokens prefetched 3 ahead, P rows 2 ahead.
// ---------------------------------------------------------------------------
#define UPD_DPP(SRC, CTRL) __builtin_amdgcn_update_dpp(0, (SRC), (CTRL), 0xf, 0xf, true)

#define FMAC_DPP(ACC, SRC, W, S)                                              \
    asm("v_fmac_f32_dpp %0, %1, %2 row_ror:" #S " row_mask:0xf bank_mask:0xf" \
        : "+v"(ACC) : "v"(SRC), "v"(W))

__global__ __launch_bounds__(256, 4) void rnn_scan(
    const int*   __restrict__ x,   const float* __restrict__ P,
    const float* __restrict__ Wh,  const float* __restrict__ Wd,
    const float* __restrict__ bd,  float* __restrict__ out)
{
    const int lane = threadIdx.x & 63;
    const int g    = lane & 31;                       // j index within batch
    const int wid  = (blockIdx.x * 256 + threadIdx.x) >> 6;
    const int b    = wid * 2 + (lane >> 5);           // batch for this half-wave

    // --- index tables via the same DPP control as the hot loop -------------
    int idxs[16];
    idxs[0] = g;
#define MKIDX(S) idxs[S] = UPD_DPP(g, 0x120 + S);     /* row_ror:S */
    MKIDX(1)  MKIDX(2)  MKIDX(3)  MKIDX(4)  MKIDX(5)
    MKIDX(6)  MKIDX(7)  MKIDX(8)  MKIDX(9)  MKIDX(10)
    MKIDX(11) MKIDX(12) MKIDX(13) MKIDX(14) MKIDX(15)
#undef MKIDX

    // w0[s]: weight matching ror:s of h; w1[s]: matching ror:s of hswz
    float w0[16], w1[16];
#pragma unroll
    for (int s = 0; s < 16; ++s) {
        w0[s] = Wh[idxs[s] * HID + g];
        w1[s] = Wh[(idxs[s] ^ 16) * HID + g];
    }

    const int* xb = x + b * TLEN;

    // software pipeline: pA = P(t), pB = P(t+1), tok2 = token(t+2)
    int   tok2 = xb[2];
    float pA = P[xb[0] * HID + g];
    float pB = P[xb[1] * HID + g];

    float h = 0.0f, hswz = 0.0f;
    const float TWO_LOG2E = 2.8853900817779268f;      // 2*log2(e)

    for (int t = 0; t < TLEN; ++t) {
        // prefetch token(t+3) (clamped in-bounds; value unused for tail) and
        // issue P(t+2) using the token loaded one iteration ago
        int   ti   = (t + 3 < TLEN) ? (t + 3) : (TLEN - 1);
        int   tok3 = xb[ti];
        float pC   = P[tok2 * HID + g];

        // z_j = P[tok][j] + sum_i h_i * Wh[i][j] via fmac_dpp, 2 parallel chains
        float a0 = fmaf(h, w0[0], pA);                // s=0 plain (also DPP-hazard gap)
        float a1 = hswz * w1[0];
#define STEP2(S) FMAC_DPP(a0, h, w0[S], S); FMAC_DPP(a1, hswz, w1[S], S);
        STEP2(1)  STEP2(2)  STEP2(3)  STEP2(4)  STEP2(5)
        STEP2(6)  STEP2(7)  STEP2(8)  STEP2(9)  STEP2(10)
        STEP2(11) STEP2(12) STEP2(13) STEP2(14) STEP2(15)
#undef STEP2
        float z = a0 + a1;

        // tanh(z) = 1 - 2/(e^{2z}+1); saturates cleanly (inf -> 1, 0 -> -1)
        float e2 = __builtin_amdgcn_exp2f(z * TWO_LOG2E);
        float r  = __builtin_amdgcn_rcpf(e2 + 1.0f);
        h = fmaf(-2.0f, r, 1.0f);

        // cross-16 copy for next step's second block (lane^16 within 32-group)
        hswz = __int_as_float(__builtin_amdgcn_ds_swizzle(__float_as_int(h), 0x401F));

        pA = pB; pB = pC; tok2 = tok3;
    }

    // out[b] = sigmoid(sum_j h_j * Wd[j] + bd)
    float s = h * Wd[g];
#pragma unroll
    for (int off = 16; off > 0; off >>= 1)
        s += __shfl_xor(s, off, 32);                  // reduce within 32-lane half
    if (g == 0) {
        float logit = s + bd[0];
        out[b] = 1.0f / (1.0f + __expf(-logit));      // fp32 output
    }
}

// ---------------------------------------------------------------------------
extern "C" void kernel_launch(void* const* d_in, const int* in_sizes, int n_in,
                              void* d_out, int out_size, void* d_ws, size_t ws_size,
                              hipStream_t stream)
{
    const int*   x   = (const int*)  d_in[0];
    const float* emb = (const float*)d_in[1];
    const float* Wx  = (const float*)d_in[2];
    const float* Wh  = (const float*)d_in[3];
    const float* bia = (const float*)d_in[4];
    const float* Wd  = (const float*)d_in[5];
    const float* bd  = (const float*)d_in[6];
    float* out = (float*)d_out;

    float* P = (float*)d_ws;                          // VOCAB*HID*4 = 1.28 MB

    rnn_proj<<<(VOCAB * HID + 255) / 256, 256, 0, stream>>>(emb, Wx, bia, P);
    rnn_scan<<<BATCH / 8, 256, 0, stream>>>(x, P, Wh, Wd, bd, out);
}

// Round 6
// 116.565 us; speedup vs baseline: 1.4869x; 1.4869x over previous
//
#include <hip/hip_runtime.h>

#define VOCAB 10000
#define EMB   16
#define HID   32
#define BATCH 4096
#define TLEN  512

// ---------------------------------------------------------------------------
// Kernel 1: P[v][j] = b[j] + sum_e emb[v][e] * Wx[e][j]   (fp32 table in ws)
// ---------------------------------------------------------------------------
__global__ __launch_bounds__(256) void rnn_proj(
    const float* __restrict__ emb, const float* __restrict__ Wx,
    const float* __restrict__ bias, float* __restrict__ P)
{
    int tid = blockIdx.x * 256 + threadIdx.x;
    if (tid >= VOCAB * HID) return;
    int v = tid >> 5;
    int j = tid & 31;
    float acc = bias[j];
    const float* ev = emb + v * EMB;
#pragma unroll
    for (int e = 0; e < EMB; ++e) {
        acc = fmaf(ev[e], Wx[e * HID + j], acc);
    }
    P[tid] = acc;
}

// ---------------------------------------------------------------------------
// Kernel 2: the scan (r3 structure, register-budget-pinned).
// Wave = 2 batches x 32 j-lanes. Wh column j in VGPRs. h (fp32) in
// wave-private LDS rows: broadcast float4 reads, no barriers ever.
// Tokens prefetched 3 ahead, P rows 2 ahead.
// amdgpu_waves_per_eu(2,2): exactly 2 waves/SIMD exist (2048 waves total /
// 1024 SIMDs), so give the allocator the full 256-VGPR budget — prevents
// rematerializing whc[] from global memory inside the loop (r3 showed
// VGPR_Count=32 with ~2x VALU instruction bloat).
// ---------------------------------------------------------------------------
__global__ __launch_bounds__(256)
__attribute__((amdgpu_waves_per_eu(2, 2)))
void rnn_scan(
    const int*   __restrict__ x,   const float* __restrict__ P,
    const float* __restrict__ Wh,  const float* __restrict__ Wd,
    const float* __restrict__ bd,  float* __restrict__ out)
{
    __shared__ float h_lds[8][HID];

    const int lane = threadIdx.x & 63;
    const int wave = threadIdx.x >> 6;
    const int half = lane >> 5;
    const int j    = lane & 31;
    const int hb   = wave * 2 + half;          // 0..7 (wave-private row)
    const int b    = blockIdx.x * 8 + hb;

    // Wh column j -> 32 VGPRs:  z_j = sum_i h_i * Wh[i][j]
    float whc[HID];
#pragma unroll
    for (int i = 0; i < HID; ++i) whc[i] = Wh[i * HID + j];

    h_lds[hb][j] = 0.0f;                        // h0 = 0 (wave-private, no barrier)

    const int* xb = x + b * TLEN;

    // software pipeline: pA = P(t), pB = P(t+1), tok2 = token(t+2)
    int   tok2 = xb[2];
    float pA = P[xb[0] * HID + j];
    float pB = P[xb[1] * HID + j];

    float hj = 0.0f;
    const float TWO_LOG2E = 2.8853900817779268f; // 2*log2(e)
    const float4* hrow = (const float4*)h_lds[hb];

    for (int t = 0; t < TLEN; ++t) {
        // prefetch token(t+3) (wave-uniform select -> scalar); issue P(t+2)
        int   ti   = (t + 3 < TLEN) ? (t + 3) : (TLEN - 1);
        int   tok3 = xb[ti];
        float pC   = P[tok2 * HID + j];

        // z_j = P[tok][j] + sum_i h_i*Wh[i][j]: fused gather+FMA, 8 chains
        float a0 = pA,  a1 = 0.f, a2 = 0.f, a3 = 0.f;
        float a4 = 0.f, a5 = 0.f, a6 = 0.f, a7 = 0.f;
#pragma unroll
        for (int q = 0; q < 4; ++q) {
            float4 hv = hrow[2 * q];
            float4 hw = hrow[2 * q + 1];
            a0 = fmaf(hv.x, whc[8 * q + 0], a0);
            a1 = fmaf(hv.y, whc[8 * q + 1], a1);
            a2 = fmaf(hv.z, whc[8 * q + 2], a2);
            a3 = fmaf(hv.w, whc[8 * q + 3], a3);
            a4 = fmaf(hw.x, whc[8 * q + 4], a4);
            a5 = fmaf(hw.y, whc[8 * q + 5], a5);
            a6 = fmaf(hw.z, whc[8 * q + 6], a6);
            a7 = fmaf(hw.w, whc[8 * q + 7], a7);
        }
        float z = ((a0 + a1) + (a2 + a3)) + ((a4 + a5) + (a6 + a7));

        // tanh(z) = 1 - 2/(e^{2z}+1); saturates cleanly (inf -> 1, 0 -> -1)
        float e2 = __builtin_amdgcn_exp2f(z * TWO_LOG2E);
        float r  = __builtin_amdgcn_rcpf(e2 + 1.0f);
        hj = fmaf(-2.0f, r, 1.0f);

        h_lds[hb][j] = hj;                      // visible to this wave next iter

        pA = pB; pB = pC; tok2 = tok3;
    }

    // out[b] = sigmoid(sum_j h_j * Wd[j] + bd)
    float s = hj * Wd[j];
#pragma unroll
    for (int off = 16; off > 0; off >>= 1)
        s += __shfl_xor(s, off, 32);            // reduce within 32-lane half
    if (j == 0) {
        float logit = s + bd[0];
        out[b] = 1.0f / (1.0f + __expf(-logit)); // fp32 output
    }
}

// ---------------------------------------------------------------------------
extern "C" void kernel_launch(void* const* d_in, const int* in_sizes, int n_in,
                              void* d_out, int out_size, void* d_ws, size_t ws_size,
                              hipStream_t stream)
{
    const int*   x   = (const int*)  d_in[0];
    const float* emb = (const float*)d_in[1];
    const float* Wx  = (const float*)d_in[2];
    const float* Wh  = (const float*)d_in[3];
    const float* bia = (const float*)d_in[4];
    const float* Wd  = (const float*)d_in[5];
    const float* bd  = (const float*)d_in[6];
    float* out = (float*)d_out;

    float* P = (float*)d_ws;                    // VOCAB*HID*4 = 1.28 MB

    rnn_proj<<<(VOCAB * HID + 255) / 256, 256, 0, stream>>>(emb, Wx, bia, P);
    rnn_scan<<<BATCH / 8, 256, 0, stream>>>(x, P, Wh, Wd, bd, out);
}